// Round 2
// baseline (42203.738 us; speedup 1.0000x reference)
//
#include <hip/hip_runtime.h>
#include <hip/hip_bf16.h>
#include <hip/hip_fp16.h>

#define T_LEN 32768
#define NDIM 256
#define NFFN 1024

typedef __attribute__((ext_vector_type(8))) short bf8v;   // 8 bf16 (4 VGPRs)
typedef __attribute__((ext_vector_type(4))) float f4v;    // MFMA accum
typedef _Float16 fp16_t;
typedef __attribute__((ext_vector_type(2))) _Float16 h2v;

__device__ __forceinline__ unsigned short f2bf(float f) {
  union { float f; unsigned int i; } v; v.f = f;
  unsigned int u = v.i;
  u += 0x7FFFu + ((u >> 16) & 1u);   // RNE
  return (unsigned short)(u >> 16);
}
__device__ __forceinline__ h2v bc2(int x) {
  union { int i; h2v h; } u; u.i = x; return u.h;
}
__device__ __forceinline__ float fdot2h(h2v a, h2v b, float c) {
#if __has_builtin(__builtin_amdgcn_fdot2)
  return __builtin_amdgcn_fdot2(a, b, c, false);
#else
  return c + (float)a.x * (float)b.x + (float)a.y * (float)b.y;
#endif
}

// A/B fragment loaders for mfma_f32_16x16x32_bf16.
// A row-major [M,K]: lane holds A[r0+(lane&15)][k0 + (lane>>4)*8 + j], j=0..7.
// B supplied as B^T row-major [N,K]: same addressing with r0 = col0.
__device__ __forceinline__ bf8v load_frag(const unsigned short* base, int ld, int r0, int k0) {
  int lane = threadIdx.x & 63;
  const unsigned short* p = base + (size_t)(r0 + (lane & 15)) * ld + (k0 + ((lane >> 4) << 3));
  return *(const bf8v*)p;
}
// Same fragment, but source tensor is f32: convert 8 floats -> bf16x8 in-register.
__device__ __forceinline__ bf8v load_frag_f32(const float* base, int ld, int r0, int k0) {
  int lane = threadIdx.x & 63;
  const float* p = base + (size_t)(r0 + (lane & 15)) * ld + (k0 + ((lane >> 4) << 3));
  float4 u = *(const float4*)p;
  float4 v = *(const float4*)(p + 4);
  bf8v r;
  r[0] = (short)f2bf(u.x); r[1] = (short)f2bf(u.y); r[2] = (short)f2bf(u.z); r[3] = (short)f2bf(u.w);
  r[4] = (short)f2bf(v.x); r[5] = (short)f2bf(v.y); r[6] = (short)f2bf(v.z); r[7] = (short)f2bf(v.w);
  return r;
}

// ---------------- K0a: transpose f32 [K,N] -> bf16 [N,K] ----------------
__global__ __launch_bounds__(256) void k_tr_bf(const float* __restrict__ src,
                                               unsigned short* __restrict__ dst, int K, int N) {
  int idx = blockIdx.x * 256 + threadIdx.x;
  if (idx >= K * N) return;
  int k = idx / N, n = idx - k * N;
  dst[n * K + k] = f2bf(src[idx]);
}
// ---------------- K0b: transpose f32 [K,N] -> f16 [N,K] (for GRU Wh) ----------------
__global__ __launch_bounds__(256) void k_tr_h(const float* __restrict__ src,
                                              fp16_t* __restrict__ dst, int K, int N) {
  int idx = blockIdx.x * 256 + threadIdx.x;
  if (idx >= K * N) return;
  int k = idx / N, n = idx - k * N;
  dst[n * K + k] = (fp16_t)src[idx];
}

// ---------------- K1: xg = xs @ Wi  ([T,256]f32 @ [256,768] -> f16 [T,768]) ----------------
__global__ __launch_bounds__(256) void k_xg(const float* __restrict__ xs,
                                            const unsigned short* __restrict__ WiT,
                                            __half* __restrict__ xg) {
  int mt = blockIdx.x, ns = blockIdx.y;
  int wave = threadIdx.x >> 6, lane = threadIdx.x & 63;
  int r0 = mt * 16;
  f4v acc[4];
#pragma unroll
  for (int i = 0; i < 4; ++i) acc[i] = (f4v){0.f, 0.f, 0.f, 0.f};
#pragma unroll
  for (int kc = 0; kc < 256; kc += 32) {
    bf8v a = load_frag_f32(xs, NDIM, r0, kc);
#pragma unroll
    for (int nt = 0; nt < 4; ++nt) {
      int c0 = ns * 256 + wave * 64 + nt * 16;
      bf8v b = load_frag(WiT, NDIM, c0, kc);
      acc[nt] = __builtin_amdgcn_mfma_f32_16x16x32_bf16(a, b, acc[nt], 0, 0, 0);
    }
  }
#pragma unroll
  for (int nt = 0; nt < 4; ++nt) {
    int col = ns * 256 + wave * 64 + nt * 16 + (lane & 15);
    int rb = r0 + ((lane >> 4) << 2);
#pragma unroll
    for (int r = 0; r < 4; ++r)
      xg[(size_t)(rb + r) * 768 + col] = (__half)acc[nt][r];
  }
}

// ---------------- K2: sequential GRU scan (single workgroup, 768 threads) ----------------
// Thread j owns Wh column j as 128 packed f16x2 registers. Per step: 128 v_dot2_f32_f16.
__global__ __launch_bounds__(768) void k_gru(const fp16_t* __restrict__ WhT,
                                             const float* __restrict__ bh,
                                             const float* __restrict__ h0,
                                             const __half* __restrict__ xg,
                                             unsigned short* __restrict__ relu_ys) {
  __shared__ float hg[768];
  __shared__ __align__(16) fp16_t hbuf[256];
  int j = threadIdx.x;

  h2v w[128];
  {
    const int4* col = (const int4*)(WhT + (size_t)j * 256);
#pragma unroll
    for (int i = 0; i < 32; ++i) {
      int4 q = col[i];
      w[4 * i + 0] = bc2(q.x); w[4 * i + 1] = bc2(q.y);
      w[4 * i + 2] = bc2(q.z); w[4 * i + 3] = bc2(q.w);
    }
  }
  float bhj = bh[j];
  float h = 0.f, xr = 0.f, xz = 0.f, xn = 0.f;
  if (j < 256) {
    h = h0[j];
    hbuf[j] = (fp16_t)h;
    xr = (float)xg[j];
    xz = (float)xg[256 + j];
    xn = (float)xg[512 + j];
  }
  __syncthreads();

  for (int t = 0; t < T_LEN; ++t) {
    float a0 = bhj, a1 = 0.f, a2 = 0.f, a3 = 0.f;
    const int4* hb = (const int4*)hbuf;
#pragma unroll
    for (int i = 0; i < 32; ++i) {
      int4 hv = hb[i];
      a0 = fdot2h(w[4 * i + 0], bc2(hv.x), a0);
      a1 = fdot2h(w[4 * i + 1], bc2(hv.y), a1);
      a2 = fdot2h(w[4 * i + 2], bc2(hv.z), a2);
      a3 = fdot2h(w[4 * i + 3], bc2(hv.w), a3);
    }
    hg[j] = (a0 + a1) + (a2 + a3);
    __syncthreads();
    if (j < 256) {
      float hr = hg[j], hz = hg[256 + j], hn = hg[512 + j];
      float r = 1.f / (1.f + __expf(-(xr + hr)));
      float z = 1.f / (1.f + __expf(-(xz + hz)));
      float ar = xn + r * hn;
      float e = __expf(-2.f * fabsf(ar));
      float th = copysignf((1.f - e) / (1.f + e), ar);   // tanh, NaN-safe
      h = (1.f - z) * th + z * h;
      hbuf[j] = (fp16_t)h;
      relu_ys[(size_t)t * NDIM + j] = f2bf(fmaxf(h, 0.f));
      int tn = (t + 1 < T_LEN) ? t + 1 : t;  // prefetch next step's xg row
      const __half* row = xg + (size_t)tn * 768;
      xr = (float)row[j];
      xz = (float)row[256 + j];
      xn = (float)row[512 + j];
    }
    __syncthreads();
  }
}

// ---------------- K3: y = LN(xs + relu(ys)@Wg + bg) * g1 + be1  (y: f32) ----------------
__global__ __launch_bounds__(256) void k_res_ln1(const unsigned short* __restrict__ rys,
                                                 const unsigned short* __restrict__ WgT,
                                                 const float* __restrict__ xs,
                                                 const float* __restrict__ bg,
                                                 const float* __restrict__ g1,
                                                 const float* __restrict__ be1,
                                                 float* __restrict__ y) {
  __shared__ float sbuf[16][264];
  int mt = blockIdx.x, tid = threadIdx.x;
  int wave = tid >> 6, lane = tid & 63;
  int r0 = mt * 16;
  f4v acc[4];
#pragma unroll
  for (int i = 0; i < 4; ++i) acc[i] = (f4v){0.f, 0.f, 0.f, 0.f};
#pragma unroll
  for (int kc = 0; kc < 256; kc += 32) {
    bf8v a = load_frag(rys, NDIM, r0, kc);
#pragma unroll
    for (int nt = 0; nt < 4; ++nt) {
      bf8v b = load_frag(WgT, NDIM, wave * 64 + nt * 16, kc);
      acc[nt] = __builtin_amdgcn_mfma_f32_16x16x32_bf16(a, b, acc[nt], 0, 0, 0);
    }
  }
#pragma unroll
  for (int nt = 0; nt < 4; ++nt) {
    int col = wave * 64 + nt * 16 + (lane & 15);
    int rl = ((lane >> 4) << 2);
#pragma unroll
    for (int r = 0; r < 4; ++r)
      sbuf[rl + r][col] = acc[nt][r] + xs[(size_t)(r0 + rl + r) * NDIM + col] + bg[col];
  }
  __syncthreads();
  int rr = tid >> 4, c0 = tid & 15;
  float sum = 0.f, sq = 0.f;
#pragma unroll
  for (int m = 0; m < 16; ++m) {
    float v = sbuf[rr][c0 + 16 * m];
    sum += v; sq += v * v;
  }
#pragma unroll
  for (int o = 1; o < 16; o <<= 1) {
    sum += __shfl_xor(sum, o, 16);
    sq  += __shfl_xor(sq, o, 16);
  }
  float mu = sum * (1.f / 256.f);
  float var = sq * (1.f / 256.f) - mu * mu;
  float rs = rsqrtf(var + 1e-6f);
#pragma unroll
  for (int m = 0; m < 16; ++m) {
    int col = c0 + 16 * m;
    float v = (sbuf[rr][col] - mu) * rs * g1[col] + be1[col];
    y[(size_t)(r0 + rr) * NDIM + col] = v;
  }
}

// ---------------- K4: out = LN(y + relu(y@W1+b1)@W2 + b2) * g2 + be2 ----------------
__global__ __launch_bounds__(256) void k_ffn(const float* __restrict__ y,
                                             const unsigned short* __restrict__ W1T,
                                             const float* __restrict__ b1,
                                             const unsigned short* __restrict__ W2T,
                                             const float* __restrict__ b2,
                                             const float* __restrict__ g2,
                                             const float* __restrict__ be2,
                                             float* __restrict__ out) {
  __shared__ unsigned short hidb[16][1032];
  __shared__ float sbuf[16][264];
  int mt = blockIdx.x, tid = threadIdx.x;
  int wave = tid >> 6, lane = tid & 63;
  int r0 = mt * 16;

  // stage 1: hid = relu(y@W1 + b1), per wave 256 cols
  f4v acc1[16];
#pragma unroll
  for (int i = 0; i < 16; ++i) acc1[i] = (f4v){0.f, 0.f, 0.f, 0.f};
#pragma unroll
  for (int kc = 0; kc < 256; kc += 32) {
    bf8v a = load_frag_f32(y, NDIM, r0, kc);
#pragma unroll
    for (int nt = 0; nt < 16; ++nt) {
      bf8v b = load_frag(W1T, NDIM, wave * 256 + nt * 16, kc);
      acc1[nt] = __builtin_amdgcn_mfma_f32_16x16x32_bf16(a, b, acc1[nt], 0, 0, 0);
    }
  }
#pragma unroll
  for (int nt = 0; nt < 16; ++nt) {
    int col = wave * 256 + nt * 16 + (lane & 15);
    int rl = ((lane >> 4) << 2);
#pragma unroll
    for (int r = 0; r < 4; ++r)
      hidb[rl + r][col] = f2bf(fmaxf(acc1[nt][r] + b1[col], 0.f));
  }
  __syncthreads();

  // stage 2: s = hid @ W2 (K=1024), A-frags from LDS
  f4v acc2[4];
#pragma unroll
  for (int i = 0; i < 4; ++i) acc2[i] = (f4v){0.f, 0.f, 0.f, 0.f};
  for (int kc = 0; kc < 1024; kc += 32) {
    bf8v a = *(const bf8v*)(&hidb[lane & 15][kc + ((lane >> 4) << 3)]);
#pragma unroll
    for (int nt = 0; nt < 4; ++nt) {
      bf8v b = load_frag(W2T, NFFN, wave * 64 + nt * 16, kc);
      acc2[nt] = __builtin_amdgcn_mfma_f32_16x16x32_bf16(a, b, acc2[nt], 0, 0, 0);
    }
  }
#pragma unroll
  for (int nt = 0; nt < 4; ++nt) {
    int col = wave * 64 + nt * 16 + (lane & 15);
    int rl = ((lane >> 4) << 2);
#pragma unroll
    for (int r = 0; r < 4; ++r)
      sbuf[rl + r][col] = acc2[nt][r] + y[(size_t)(r0 + rl + r) * NDIM + col] + b2[col];
  }
  __syncthreads();
  int rr = tid >> 4, c0 = tid & 15;
  float sum = 0.f, sq = 0.f;
#pragma unroll
  for (int m = 0; m < 16; ++m) {
    float v = sbuf[rr][c0 + 16 * m];
    sum += v; sq += v * v;
  }
#pragma unroll
  for (int o = 1; o < 16; o <<= 1) {
    sum += __shfl_xor(sum, o, 16);
    sq  += __shfl_xor(sq, o, 16);
  }
  float mu = sum * (1.f / 256.f);
  float var = sq * (1.f / 256.f) - mu * mu;
  float rs = rsqrtf(var + 1e-6f);
#pragma unroll
  for (int m = 0; m < 16; ++m) {
    int col = c0 + 16 * m;
    float v = (sbuf[rr][col] - mu) * rs * g2[col] + be2[col];
    out[(size_t)(r0 + rr) * NDIM + col] = v;
  }
}

// ---------------- host ----------------
extern "C" void kernel_launch(void* const* d_in, const int* in_sizes, int n_in,
                              void* d_out, int out_size, void* d_ws, size_t ws_size,
                              hipStream_t stream) {
  const float* xs  = (const float*)d_in[0];
  const float* h0  = (const float*)d_in[1];
  const float* Wi  = (const float*)d_in[2];
  const float* Wh  = (const float*)d_in[3];
  const float* bh  = (const float*)d_in[4];
  const float* Wg  = (const float*)d_in[5];
  const float* bg  = (const float*)d_in[6];
  const float* g1  = (const float*)d_in[7];
  const float* be1 = (const float*)d_in[8];
  const float* W1  = (const float*)d_in[9];
  const float* b1  = (const float*)d_in[10];
  const float* W2  = (const float*)d_in[11];
  const float* b2  = (const float*)d_in[12];
  const float* g2  = (const float*)d_in[13];
  const float* be2 = (const float*)d_in[14];

  char* ws = (char*)d_ws;
  // Region B: xg (f16, T*768*2 = 50331648 B), later reused for y (f32, 33554432 B)
  __half* xg = (__half*)(ws + 0);
  float*  yb = (float*)(ws + 0);          // overwrites xg AFTER k_gru consumed it
  // Region A: rys bf16 (T*256*2 = 16777216 B)
  unsigned short* rys = (unsigned short*)(ws + 50331648);
  // Region C: transposed/converted weights
  unsigned short* WiT = (unsigned short*)(ws + 67108864);   // 768*256*2 = 393216
  fp16_t*         WhT = (fp16_t*)        (ws + 67502080);   // 768*256*2 = 393216
  unsigned short* WgT = (unsigned short*)(ws + 67895296);   // 256*256*2 = 131072
  unsigned short* W1T = (unsigned short*)(ws + 68026368);   // 1024*256*2 = 524288
  unsigned short* W2T = (unsigned short*)(ws + 68550656);   // 256*1024*2 = 524288

  k_tr_bf<<<(256 * 768 + 255) / 256, 256, 0, stream>>>(Wi, WiT, 256, 768);
  k_tr_h <<<(256 * 768 + 255) / 256, 256, 0, stream>>>(Wh, WhT, 256, 768);
  k_tr_bf<<<(256 * 256 + 255) / 256, 256, 0, stream>>>(Wg, WgT, 256, 256);
  k_tr_bf<<<(256 * 1024 + 255) / 256, 256, 0, stream>>>(W1, W1T, 256, 1024);
  k_tr_bf<<<(1024 * 256 + 255) / 256, 256, 0, stream>>>(W2, W2T, 1024, 256);

  k_xg<<<dim3(T_LEN / 16, 3), 256, 0, stream>>>(xs, WiT, xg);
  k_gru<<<1, 768, 0, stream>>>(WhT, bh, h0, xg, rys);
  k_res_ln1<<<T_LEN / 16, 256, 0, stream>>>(rys, WgT, xs, bg, g1, be1, yb);
  k_ffn<<<T_LEN / 16, 256, 0, stream>>>(yb, W1T, b1, W2T, b2, g2, be2, (float*)d_out);
}

// Round 3
// 39395.020 us; speedup vs baseline: 1.0713x; 1.0713x over previous
//
#include <hip/hip_runtime.h>
#include <hip/hip_bf16.h>
#include <hip/hip_fp16.h>

#define T_LEN 32768
#define NDIM 256
#define NFFN 1024

typedef __attribute__((ext_vector_type(8))) short bf8v;   // 8 bf16 (4 VGPRs)
typedef __attribute__((ext_vector_type(4))) float f4v;    // MFMA accum
typedef _Float16 fp16_t;
typedef __attribute__((ext_vector_type(2))) _Float16 h2v;

__device__ __forceinline__ unsigned short f2bf(float f) {
  union { float f; unsigned int i; } v; v.f = f;
  unsigned int u = v.i;
  u += 0x7FFFu + ((u >> 16) & 1u);   // RNE
  return (unsigned short)(u >> 16);
}
__device__ __forceinline__ h2v bc2(int x) {
  union { int i; h2v h; } u; u.i = x; return u.h;
}
__device__ __forceinline__ float fdot2h(h2v a, h2v b, float c) {
#if __has_builtin(__builtin_amdgcn_fdot2)
  return __builtin_amdgcn_fdot2(a, b, c, false);
#else
  return c + (float)a.x * (float)b.x + (float)a.y * (float)b.y;
#endif
}

// A/B fragment loaders for mfma_f32_16x16x32_bf16.
__device__ __forceinline__ bf8v load_frag(const unsigned short* base, int ld, int r0, int k0) {
  int lane = threadIdx.x & 63;
  const unsigned short* p = base + (size_t)(r0 + (lane & 15)) * ld + (k0 + ((lane >> 4) << 3));
  return *(const bf8v*)p;
}
__device__ __forceinline__ bf8v load_frag_f32(const float* base, int ld, int r0, int k0) {
  int lane = threadIdx.x & 63;
  const float* p = base + (size_t)(r0 + (lane & 15)) * ld + (k0 + ((lane >> 4) << 3));
  float4 u = *(const float4*)p;
  float4 v = *(const float4*)(p + 4);
  bf8v r;
  r[0] = (short)f2bf(u.x); r[1] = (short)f2bf(u.y); r[2] = (short)f2bf(u.z); r[3] = (short)f2bf(u.w);
  r[4] = (short)f2bf(v.x); r[5] = (short)f2bf(v.y); r[6] = (short)f2bf(v.z); r[7] = (short)f2bf(v.w);
  return r;
}

// ---------------- K0a: transpose f32 [K,N] -> bf16 [N,K] ----------------
__global__ __launch_bounds__(256) void k_tr_bf(const float* __restrict__ src,
                                               unsigned short* __restrict__ dst, int K, int N) {
  int idx = blockIdx.x * 256 + threadIdx.x;
  if (idx >= K * N) return;
  int k = idx / N, n = idx - k * N;
  dst[n * K + k] = f2bf(src[idx]);
}
// ---------------- K0b: transpose f32 [K,N] -> f16 [N,K] (for GRU Wh) ----------------
__global__ __launch_bounds__(256) void k_tr_h(const float* __restrict__ src,
                                              fp16_t* __restrict__ dst, int K, int N) {
  int idx = blockIdx.x * 256 + threadIdx.x;
  if (idx >= K * N) return;
  int k = idx / N, n = idx - k * N;
  dst[n * K + k] = (fp16_t)src[idx];
}

// ---------------- K1: xg = xs @ Wi  ([T,256]f32 @ [256,768] -> f16 [T,768]) ----------------
__global__ __launch_bounds__(256) void k_xg(const float* __restrict__ xs,
                                            const unsigned short* __restrict__ WiT,
                                            __half* __restrict__ xg) {
  int mt = blockIdx.x, ns = blockIdx.y;
  int wave = threadIdx.x >> 6, lane = threadIdx.x & 63;
  int r0 = mt * 16;
  f4v acc[4];
#pragma unroll
  for (int i = 0; i < 4; ++i) acc[i] = (f4v){0.f, 0.f, 0.f, 0.f};
#pragma unroll
  for (int kc = 0; kc < 256; kc += 32) {
    bf8v a = load_frag_f32(xs, NDIM, r0, kc);
#pragma unroll
    for (int nt = 0; nt < 4; ++nt) {
      int c0 = ns * 256 + wave * 64 + nt * 16;
      bf8v b = load_frag(WiT, NDIM, c0, kc);
      acc[nt] = __builtin_amdgcn_mfma_f32_16x16x32_bf16(a, b, acc[nt], 0, 0, 0);
    }
  }
#pragma unroll
  for (int nt = 0; nt < 4; ++nt) {
    int col = ns * 256 + wave * 64 + nt * 16 + (lane & 15);
    int rb = r0 + ((lane >> 4) << 2);
#pragma unroll
    for (int r = 0; r < 4; ++r)
      xg[(size_t)(rb + r) * 768 + col] = (__half)acc[nt][r];
  }
}

// ---------------- K2: sequential GRU scan ----------------
// 512 threads (8 waves, 2/SIMD). Lane (wv, g=lane&15, q=lane>>4) owns
// cols {96*wv + 6*g + i, i=0..5} restricted to K-quarter [64q, 64q+64).
// Weights register-resident: w[6][32] f16x2 = 192 VGPRs.
// Per step: 8x ds_read_b128 (h quarter, 64KB/step CU-wide), 192 v_dot2,
// partials to LDS, gate threads (j<256) sum 4 partials per gate column.
__global__ __launch_bounds__(512, 2) void k_gru(const fp16_t* __restrict__ WhT,
                                                const float* __restrict__ bh,
                                                const float* __restrict__ h0,
                                                const __half* __restrict__ xg,
                                                unsigned short* __restrict__ relu_ys) {
  __shared__ float P[4][776];                 // [quarter][col], stride 776 to spread banks
  __shared__ __align__(16) fp16_t hbuf[256];
  const int j = threadIdx.x;
  const int wv = j >> 6, lane = j & 63;
  const int q = lane >> 4, g = lane & 15;
  const int cbase = 96 * wv + 6 * g;

  // Load this thread's weight block: 6 cols x 64 K-elems (quarter q), f16.
  h2v w[6][32];
#pragma unroll
  for (int i = 0; i < 6; ++i) {
    const int4* cp = (const int4*)(WhT + (size_t)(cbase + i) * 256 + q * 64);
#pragma unroll
    for (int k = 0; k < 8; ++k) {
      int4 v = cp[k];
      w[i][4 * k + 0] = bc2(v.x); w[i][4 * k + 1] = bc2(v.y);
      w[i][4 * k + 2] = bc2(v.z); w[i][4 * k + 3] = bc2(v.w);
    }
  }

  float bhr = 0.f, bhz = 0.f, bhn = 0.f;
  float h = 0.f, xr = 0.f, xz = 0.f, xn = 0.f;
  if (j < 256) {
    bhr = bh[j]; bhz = bh[256 + j]; bhn = bh[512 + j];
    h = h0[j];
    hbuf[j] = (fp16_t)h;
    xr = (float)xg[j];
    xz = (float)xg[256 + j];
    xn = (float)xg[512 + j];
  }
  __syncthreads();

  const int4* hb4 = (const int4*)hbuf;   // 32 int4; quarter q = hb4[8q .. 8q+7]
  for (int t = 0; t < T_LEN; ++t) {
    // ---- phase 1: partial matvec over this thread's K-quarter ----
    float acc[6];
#pragma unroll
    for (int i = 0; i < 6; ++i) acc[i] = 0.f;
#pragma unroll
    for (int ch = 0; ch < 8; ++ch) {
      int4 hv = hb4[q * 8 + ch];
      h2v p0 = bc2(hv.x), p1 = bc2(hv.y), p2 = bc2(hv.z), p3 = bc2(hv.w);
#pragma unroll
      for (int i = 0; i < 6; ++i) {
        acc[i] = fdot2h(w[i][4 * ch + 0], p0, acc[i]);
        acc[i] = fdot2h(w[i][4 * ch + 1], p1, acc[i]);
        acc[i] = fdot2h(w[i][4 * ch + 2], p2, acc[i]);
        acc[i] = fdot2h(w[i][4 * ch + 3], p3, acc[i]);
      }
    }
    // write 6 partials as 3x ds_write_b64 (8B-aligned: cbase*4 = 24g mod 8 == 0)
    float* pp = &P[q][cbase];
    ((float2*)pp)[0] = make_float2(acc[0], acc[1]);
    ((float2*)pp)[1] = make_float2(acc[2], acc[3]);
    ((float2*)pp)[2] = make_float2(acc[4], acc[5]);
    __syncthreads();

    // ---- phase 2: gates on threads 0..255 ----
    if (j < 256) {
      float hr = bhr, hz = bhz, hn = bhn;
#pragma unroll
      for (int qq = 0; qq < 4; ++qq) {
        hr += P[qq][j];
        hz += P[qq][256 + j];
        hn += P[qq][512 + j];
      }
      float r = 1.f / (1.f + __expf(-(xr + hr)));
      float z = 1.f / (1.f + __expf(-(xz + hz)));
      float ar = xn + r * hn;
      float e = __expf(-2.f * fabsf(ar));
      float th = copysignf((1.f - e) / (1.f + e), ar);   // tanh, NaN-safe
      h = (1.f - z) * th + z * h;
      hbuf[j] = (fp16_t)h;
      relu_ys[(size_t)t * NDIM + j] = f2bf(fmaxf(h, 0.f));
      int tn = (t + 1 < T_LEN) ? t + 1 : t;  // prefetch next step's xg row
      const __half* row = xg + (size_t)tn * 768;
      xr = (float)row[j];
      xz = (float)row[256 + j];
      xn = (float)row[512 + j];
    }
    __syncthreads();
  }
}

// ---------------- K3: y = LN(xs + relu(ys)@Wg + bg) * g1 + be1  (y: f32) ----------------
__global__ __launch_bounds__(256) void k_res_ln1(const unsigned short* __restrict__ rys,
                                                 const unsigned short* __restrict__ WgT,
                                                 const float* __restrict__ xs,
                                                 const float* __restrict__ bg,
                                                 const float* __restrict__ g1,
                                                 const float* __restrict__ be1,
                                                 float* __restrict__ y) {
  __shared__ float sbuf[16][264];
  int mt = blockIdx.x, tid = threadIdx.x;
  int wave = tid >> 6, lane = tid & 63;
  int r0 = mt * 16;
  f4v acc[4];
#pragma unroll
  for (int i = 0; i < 4; ++i) acc[i] = (f4v){0.f, 0.f, 0.f, 0.f};
#pragma unroll
  for (int kc = 0; kc < 256; kc += 32) {
    bf8v a = load_frag(rys, NDIM, r0, kc);
#pragma unroll
    for (int nt = 0; nt < 4; ++nt) {
      bf8v b = load_frag(WgT, NDIM, wave * 64 + nt * 16, kc);
      acc[nt] = __builtin_amdgcn_mfma_f32_16x16x32_bf16(a, b, acc[nt], 0, 0, 0);
    }
  }
#pragma unroll
  for (int nt = 0; nt < 4; ++nt) {
    int col = wave * 64 + nt * 16 + (lane & 15);
    int rl = ((lane >> 4) << 2);
#pragma unroll
    for (int r = 0; r < 4; ++r)
      sbuf[rl + r][col] = acc[nt][r] + xs[(size_t)(r0 + rl + r) * NDIM + col] + bg[col];
  }
  __syncthreads();
  int rr = tid >> 4, c0 = tid & 15;
  float sum = 0.f, sq = 0.f;
#pragma unroll
  for (int m = 0; m < 16; ++m) {
    float v = sbuf[rr][c0 + 16 * m];
    sum += v; sq += v * v;
  }
#pragma unroll
  for (int o = 1; o < 16; o <<= 1) {
    sum += __shfl_xor(sum, o, 16);
    sq  += __shfl_xor(sq, o, 16);
  }
  float mu = sum * (1.f / 256.f);
  float var = sq * (1.f / 256.f) - mu * mu;
  float rs = rsqrtf(var + 1e-6f);
#pragma unroll
  for (int m = 0; m < 16; ++m) {
    int col = c0 + 16 * m;
    float v = (sbuf[rr][col] - mu) * rs * g1[col] + be1[col];
    y[(size_t)(r0 + rr) * NDIM + col] = v;
  }
}

// ---------------- K4: out = LN(y + relu(y@W1+b1)@W2 + b2) * g2 + be2 ----------------
__global__ __launch_bounds__(256) void k_ffn(const float* __restrict__ y,
                                             const unsigned short* __restrict__ W1T,
                                             const float* __restrict__ b1,
                                             const unsigned short* __restrict__ W2T,
                                             const float* __restrict__ b2,
                                             const float* __restrict__ g2,
                                             const float* __restrict__ be2,
                                             float* __restrict__ out) {
  __shared__ unsigned short hidb[16][1032];
  __shared__ float sbuf[16][264];
  int mt = blockIdx.x, tid = threadIdx.x;
  int wave = tid >> 6, lane = tid & 63;
  int r0 = mt * 16;

  f4v acc1[16];
#pragma unroll
  for (int i = 0; i < 16; ++i) acc1[i] = (f4v){0.f, 0.f, 0.f, 0.f};
#pragma unroll
  for (int kc = 0; kc < 256; kc += 32) {
    bf8v a = load_frag_f32(y, NDIM, r0, kc);
#pragma unroll
    for (int nt = 0; nt < 16; ++nt) {
      bf8v b = load_frag(W1T, NDIM, wave * 256 + nt * 16, kc);
      acc1[nt] = __builtin_amdgcn_mfma_f32_16x16x32_bf16(a, b, acc1[nt], 0, 0, 0);
    }
  }
#pragma unroll
  for (int nt = 0; nt < 16; ++nt) {
    int col = wave * 256 + nt * 16 + (lane & 15);
    int rl = ((lane >> 4) << 2);
#pragma unroll
    for (int r = 0; r < 4; ++r)
      hidb[rl + r][col] = f2bf(fmaxf(acc1[nt][r] + b1[col], 0.f));
  }
  __syncthreads();

  f4v acc2[4];
#pragma unroll
  for (int i = 0; i < 4; ++i) acc2[i] = (f4v){0.f, 0.f, 0.f, 0.f};
  for (int kc = 0; kc < 1024; kc += 32) {
    bf8v a = *(const bf8v*)(&hidb[lane & 15][kc + ((lane >> 4) << 3)]);
#pragma unroll
    for (int nt = 0; nt < 4; ++nt) {
      bf8v b = load_frag(W2T, NFFN, wave * 64 + nt * 16, kc);
      acc2[nt] = __builtin_amdgcn_mfma_f32_16x16x32_bf16(a, b, acc2[nt], 0, 0, 0);
    }
  }
#pragma unroll
  for (int nt = 0; nt < 4; ++nt) {
    int col = wave * 64 + nt * 16 + (lane & 15);
    int rl = ((lane >> 4) << 2);
#pragma unroll
    for (int r = 0; r < 4; ++r)
      sbuf[rl + r][col] = acc2[nt][r] + y[(size_t)(r0 + rl + r) * NDIM + col] + b2[col];
  }
  __syncthreads();
  int rr = tid >> 4, c0 = tid & 15;
  float sum = 0.f, sq = 0.f;
#pragma unroll
  for (int m = 0; m < 16; ++m) {
    float v = sbuf[rr][c0 + 16 * m];
    sum += v; sq += v * v;
  }
#pragma unroll
  for (int o = 1; o < 16; o <<= 1) {
    sum += __shfl_xor(sum, o, 16);
    sq  += __shfl_xor(sq, o, 16);
  }
  float mu = sum * (1.f / 256.f);
  float var = sq * (1.f / 256.f) - mu * mu;
  float rs = rsqrtf(var + 1e-6f);
#pragma unroll
  for (int m = 0; m < 16; ++m) {
    int col = c0 + 16 * m;
    float v = (sbuf[rr][col] - mu) * rs * g2[col] + be2[col];
    out[(size_t)(r0 + rr) * NDIM + col] = v;
  }
}

// ---------------- host ----------------
extern "C" void kernel_launch(void* const* d_in, const int* in_sizes, int n_in,
                              void* d_out, int out_size, void* d_ws, size_t ws_size,
                              hipStream_t stream) {
  const float* xs  = (const float*)d_in[0];
  const float* h0  = (const float*)d_in[1];
  const float* Wi  = (const float*)d_in[2];
  const float* Wh  = (const float*)d_in[3];
  const float* bh  = (const float*)d_in[4];
  const float* Wg  = (const float*)d_in[5];
  const float* bg  = (const float*)d_in[6];
  const float* g1  = (const float*)d_in[7];
  const float* be1 = (const float*)d_in[8];
  const float* W1  = (const float*)d_in[9];
  const float* b1  = (const float*)d_in[10];
  const float* W2  = (const float*)d_in[11];
  const float* b2  = (const float*)d_in[12];
  const float* g2  = (const float*)d_in[13];
  const float* be2 = (const float*)d_in[14];

  char* ws = (char*)d_ws;
  __half* xg = (__half*)(ws + 0);          // f16 [T,768] = 50331648 B
  float*  yb = (float*)(ws + 0);           // reuses xg region AFTER k_gru
  unsigned short* rys = (unsigned short*)(ws + 50331648);   // bf16 [T,256]
  unsigned short* WiT = (unsigned short*)(ws + 67108864);
  fp16_t*         WhT = (fp16_t*)        (ws + 67502080);
  unsigned short* WgT = (unsigned short*)(ws + 67895296);
  unsigned short* W1T = (unsigned short*)(ws + 68026368);
  unsigned short* W2T = (unsigned short*)(ws + 68550656);

  k_tr_bf<<<(256 * 768 + 255) / 256, 256, 0, stream>>>(Wi, WiT, 256, 768);
  k_tr_h <<<(256 * 768 + 255) / 256, 256, 0, stream>>>(Wh, WhT, 256, 768);
  k_tr_bf<<<(256 * 256 + 255) / 256, 256, 0, stream>>>(Wg, WgT, 256, 256);
  k_tr_bf<<<(256 * 1024 + 255) / 256, 256, 0, stream>>>(W1, W1T, 256, 1024);
  k_tr_bf<<<(1024 * 256 + 255) / 256, 256, 0, stream>>>(W2, W2T, 1024, 256);

  k_xg<<<dim3(T_LEN / 16, 3), 256, 0, stream>>>(xs, WiT, xg);
  k_gru<<<1, 512, 0, stream>>>(WhT, bh, h0, xg, rys);
  k_res_ln1<<<T_LEN / 16, 256, 0, stream>>>(rys, WgT, xs, bg, g1, be1, yb);
  k_ffn<<<T_LEN / 16, 256, 0, stream>>>(yb, W1T, b1, W2T, b2, g2, be2, (float*)d_out);
}